// Round 19
// baseline (228.486 us; speedup 1.0000x reference)
//
#include <hip/hip_runtime.h>
#include <hip/hip_bf16.h>
#include <cstdint>
#include <cstddef>

#define B_ 4
#define S_ 2048
#define E_ 768
#define H_ 12
#define D_ 64

typedef __bf16 bf16x8 __attribute__((ext_vector_type(8)));
typedef float f32x4 __attribute__((ext_vector_type(4)));
typedef unsigned uint32x4 __attribute__((ext_vector_type(4)));

__constant__ float c_slopes[12] = {
    0.6299605249f, 0.396850263f, 0.25f, 0.1574901312f,
    0.0992125657f, 0.0625f, 0.0393725328f, 0.0248031414f,
    0.015625f, 0.0098431332f, 0.0062007854f, 0.00390625f};

__device__ __forceinline__ unsigned short f2bf_u(float f) {
    unsigned u = __builtin_bit_cast(unsigned, f);
    u += 0x7fffu + ((u >> 16) & 1u);   // round-to-nearest-even
    return (unsigned short)(u >> 16);
}
__device__ __forceinline__ __bf16 f2bf(float f) {
    unsigned short s = f2bf_u(f);
    return __builtin_bit_cast(__bf16, s);
}

// async global->LDS, 16B per lane, dest = wave-uniform base + lane*16
__device__ __forceinline__ void gload_lds16(const void* g, void* l) {
    __builtin_amdgcn_global_load_lds(
        (const __attribute__((address_space(1))) unsigned int*)g,
        (__attribute__((address_space(3))) unsigned int*)l, 16, 0, 0);
}

// ---------------------------------------------------------------------------
// merged prep kernel. Blocks [0,6144): x fp32->bf16. Blocks [6144,6720):
// W fp32 [k][n] -> Wt bf16 [n][k].
// ---------------------------------------------------------------------------
__global__ __launch_bounds__(256) void prep(
    const float* __restrict__ x, __bf16* __restrict__ xb,
    const float* __restrict__ W0, const float* __restrict__ W1,
    const float* __restrict__ W2, const float* __restrict__ W3,
    __bf16* __restrict__ Wt) {
    __shared__ alignas(16) __bf16 ts[64 * 72];
    const int L = blockIdx.x;
    const int t = threadIdx.x;
    if (L < 6144) {
        int i = (L * 256 + t) * 4;
        float4 v = *(const float4*)(x + i);
        ushort4 o;
        o.x = f2bf_u(v.x); o.y = f2bf_u(v.y); o.z = f2bf_u(v.z); o.w = f2bf_u(v.w);
        *(ushort4*)((unsigned short*)xb + i) = o;
        return;
    }
    const int id = L - 6144;
    const int z = id / 144, rem = id % 144;
    const int k0 = (rem / 12) * 64, n0 = (rem % 12) * 64;
    const float* W = z == 0 ? W0 : z == 1 ? W1 : z == 2 ? W2 : W3;
    __bf16* out = Wt + (size_t)z * E_ * E_;
#pragma unroll
    for (int i = 0; i < 4; i++) {
        int idx = i * 256 + t;          // 1024 float4 chunks
        int row = idx >> 4, c4 = idx & 15;
        float4 v = *(const float4*)(W + (size_t)(k0 + row) * E_ + n0 + c4 * 4);
        ts[(c4 * 4 + 0) * 72 + row] = f2bf(v.x);
        ts[(c4 * 4 + 1) * 72 + row] = f2bf(v.y);
        ts[(c4 * 4 + 2) * 72 + row] = f2bf(v.z);
        ts[(c4 * 4 + 3) * 72 + row] = f2bf(v.w);
    }
    __syncthreads();
#pragma unroll
    for (int i = 0; i < 2; i++) {
        int idx = i * 256 + t;          // 512 chunks of 8 bf16
        int r = idx >> 3, c8 = idx & 7;
        *(uint4*)((unsigned short*)out + (size_t)(n0 + r) * E_ + k0 + c8 * 8) =
            *(const uint4*)((const unsigned short*)ts + r * 72 + c8 * 8);
    }
}

// ---------------------------------------------------------------------------
// FUSED QKV GEMM, R28: 64M x 64N x 3z retile for OCCUPANCY. The 128M tile
// ran at 3 waves/SIMD (768 blocks = 3/CU); R17 (drain amortization) and
// R21 (bank swizzle) were both ~null, leaving latency/TLP as the binding
// constraint - the same diagnosis attn had before R15 (3->6 waves/SIMD
// = -13%). Grid (12,128) = 1536 blocks = 6/CU = 6 waves/SIMD. Single BK32
// panel (R17 proved BK64 neutral), LDS 16KB, acc 48 VGPR; bias loads moved
// POST-loop to fit the 85-VGPR/6-wave budget. All staging/swizzle/epilogue
// index math reused verbatim from the verified 128M body (i-loop collapsed).
// ---------------------------------------------------------------------------
__global__ __launch_bounds__(256, 6) void qkv_gemm(
    const __bf16* __restrict__ A, const __bf16* __restrict__ WtAll,
    const float* __restrict__ b0, const float* __restrict__ b1,
    const float* __restrict__ b2, __bf16* __restrict__ Qb,
    __bf16* __restrict__ Kb, __bf16* __restrict__ Vtb) {
    constexpr int Kd = E_;
    __shared__ alignas(16) __bf16 Asm[64 * 32];      // 4KB
    __shared__ alignas(16) __bf16 Bsm[3][64 * 32];   // 12KB

    const int t = threadIdx.x;
    const int w = t >> 6, lane = t & 63;
    const int qm = lane & 15, quad = lane >> 4;
    const int m0 = blockIdx.y * 64, n0 = blockIdx.x * 64;
    const int wm = w * 16;                 // wave owns 16 rows x 64 cols (x3 z)

    const int crow = lane >> 2;                      // row within 16-row chunk
    const int scol = (lane & 3) ^ ((lane >> 3) & 3); // swizzled SOURCE quarter
    const int cq = (quad ^ ((qm >> 1) & 3)) * 8;     // swizzled read quarter

    f32x4 acc[3][4] = {};

    for (int k0 = 0; k0 < Kd; k0 += 32) {
        // A: 4 chunks of 16 rows; wave w stages chunk w (its own rows)
        gload_lds16((const unsigned short*)A +
                        (size_t)(m0 + w * 16 + crow) * Kd + k0 + scol * 8,
                    Asm + w * 512);
        // B: 3 z x 4 chunks = 12; wave w stages {3w, 3w+1, 3w+2}
#pragma unroll
        for (int e = 0; e < 3; e++) {
            int g = w * 3 + e;
            int z = g >> 2, cz = g & 3;
            gload_lds16((const unsigned short*)WtAll + (size_t)z * Kd * E_ +
                            (size_t)(n0 + cz * 16 + crow) * Kd + k0 + scol * 8,
                        Bsm[z] + cz * 512);
        }
        __syncthreads();

        bf16x8 af = *(const bf16x8*)(Asm + (wm + qm) * 32 + cq);
#pragma unroll
        for (int z = 0; z < 3; z++) {
            bf16x8 bg[4];
#pragma unroll
            for (int j = 0; j < 4; j++)
                bg[j] = *(const bf16x8*)(Bsm[z] + (j * 16 + qm) * 32 + cq);
#pragma unroll
            for (int j = 0; j < 4; j++)
                acc[z][j] = __builtin_amdgcn_mfma_f32_16x16x32_bf16(
                    af, bg[j], acc[z][j], 0, 0, 0);
        }
        __syncthreads();
    }

    // bias loads here (post-loop): frees 12 VGPRs across the K-loop
    float bvv[3][4];
    const float* bs[3] = {b0, b1, b2};
#pragma unroll
    for (int z = 0; z < 3; z++)
#pragma unroll
        for (int j = 0; j < 4; j++) bvv[z][j] = bs[z][n0 + j * 16 + qm];

    // epilogue: C/D layout col=lane&15, row=quad*4+reg
#pragma unroll
    for (int z = 0; z < 3; z++) {
        __bf16* out = z == 0 ? Qb : z == 1 ? Kb : Vtb;
#pragma unroll
        for (int j = 0; j < 4; j++) {
            int col = n0 + j * 16 + qm;
            int rowb = m0 + wm + quad * 4;
            int h = col >> 6, d = col & (D_ - 1);
            if (z == 2) {
                // V -> Vt [bh][d][s]: rows r consecutive s, pack 4 bf16
                int b = rowb >> 11, s = rowb & (S_ - 1);
                unsigned short pk4[4];
#pragma unroll
                for (int r = 0; r < 4; r++)
                    pk4[r] = f2bf_u(acc[z][j][r] + bvv[z][j]);
                uint2 pv;
                pv.x = (unsigned)pk4[0] | ((unsigned)pk4[1] << 16);
                pv.y = (unsigned)pk4[2] | ((unsigned)pk4[3] << 16);
                *(uint2*)((unsigned short*)out +
                          ((size_t)(b * H_ + h) * D_ + d) * S_ + s) = pv;
            } else {
#pragma unroll
                for (int r = 0; r < 4; r++) {
                    int row = rowb + r;
                    int b = row >> 11, s = row & (S_ - 1);
                    out[(((size_t)(b * H_ + h)) * S_ + s) * D_ + d] =
                        f2bf(acc[z][j][r] + bvv[z][j]);
                }
            }
        }
    }
}

// ---------------------------------------------------------------------------
// Output projection GEMM, R28: same 64M x 64N occupancy retile.
// Grid (12,128) = 1536 blocks = 6/CU; LDS 8KB; acc 16 VGPR.
// ---------------------------------------------------------------------------
__global__ __launch_bounds__(256, 6) void gemm_out(
    const __bf16* __restrict__ A, const __bf16* __restrict__ Wt,
    const float* __restrict__ bias, float* __restrict__ outF) {
    constexpr int Kd = E_, N = E_;
    __shared__ alignas(16) __bf16 Asm[64 * 32];   // 4KB
    __shared__ alignas(16) __bf16 Bsm[64 * 32];   // 4KB

    const int t = threadIdx.x;
    const int w = t >> 6, lane = t & 63;
    const int qm = lane & 15, quad = lane >> 4;
    const int m0 = blockIdx.y * 64, n0 = blockIdx.x * 64;
    const int wm = w * 16;

    const int crow = lane >> 2;
    const int scol = (lane & 3) ^ ((lane >> 3) & 3); // swizzled SOURCE quarter
    const int cq = (quad ^ ((qm >> 1) & 3)) * 8;     // swizzled read quarter

    f32x4 acc[4] = {};

    for (int k0 = 0; k0 < Kd; k0 += 32) {
        gload_lds16((const unsigned short*)A +
                        (size_t)(m0 + w * 16 + crow) * Kd + k0 + scol * 8,
                    Asm + w * 512);
        gload_lds16((const unsigned short*)Wt +
                        (size_t)(n0 + w * 16 + crow) * Kd + k0 + scol * 8,
                    Bsm + w * 512);
        __syncthreads();

        bf16x8 af = *(const bf16x8*)(Asm + (wm + qm) * 32 + cq);
        bf16x8 bg[4];
#pragma unroll
        for (int j = 0; j < 4; j++)
            bg[j] = *(const bf16x8*)(Bsm + (j * 16 + qm) * 32 + cq);
#pragma unroll
        for (int j = 0; j < 4; j++)
            acc[j] = __builtin_amdgcn_mfma_f32_16x16x32_bf16(
                af, bg[j], acc[j], 0, 0, 0);
        __syncthreads();
    }

    float bvv[4];
#pragma unroll
    for (int j = 0; j < 4; j++) bvv[j] = bias[n0 + j * 16 + qm];

#pragma unroll
    for (int j = 0; j < 4; j++) {
        int col = n0 + j * 16 + qm;
        int rowb = m0 + wm + quad * 4;
#pragma unroll
        for (int r = 0; r < 4; r++)
            outF[(size_t)(rowb + r) * N + col] = acc[j][r] + bvv[j];
    }
}

// ---------------------------------------------------------------------------
// Flash attention (R27 body, kept byte-identical - the control at 52.6us).
// Mirrored-slot exact balance; zero-LDS P via kappa row remap; unpaired;
// 6 blocks/CU; lsv f32x4. setprio blacklisted (R24).
// ---------------------------------------------------------------------------
__global__ __launch_bounds__(256, 6) void attn_k(
    const __bf16* __restrict__ Q, const __bf16* __restrict__ K,
    const __bf16* __restrict__ Vt, __bf16* __restrict__ O) {
    __shared__ alignas(16) __bf16 Ksm[2][64 * 32];   // [dhalf][key][d%32] swz
    __shared__ alignas(16) __bf16 Vsm[2][64 * 32];   // [khalf][d][key%32] swz

    const int t = threadIdx.x;
    const int w = t >> 6, lane = t & 63;
    const int qm = lane & 15, quad = lane >> 4;
    // balanced XCD-local block swizzle, mirrored-slot exact balance
    const int L = blockIdx.x;
    const int r = L & 7;            // XCD (round-robin)
    const int m = (L >> 3) & 31;    // CU within XCD
    const int s = L >> 8;           // co-resident slot 0..5
    const int bh = r * 6 + s;       // 6 fixed heads per XCD
    const int so = (s % 3) * 5 + ((s % 3) >> 1);   // 0,5,11
    const int qt = (s < 3) ? ((m + so) & 31) : ((31 - m - so) & 31);
    const float c2 = c_slopes[bh % H_] * 1.44269504f;     // slope * log2(e)
    const size_t base = (size_t)bh * S_ * D_;

    // Q B-fragments (lane qm = q-col, contiguous over d)
    const int bb = qt * 64 + w * 16;
    const __bf16* qp = Q + base + (size_t)(bb + qm) * D_ + quad * 8;
    bf16x8 qf0 = *(const bf16x8*)qp;
    bf16x8 qf1 = *(const bf16x8*)(qp + 32);

    f32x4 oacc[4] = {};
    f32x4 lsv = {0.f, 0.f, 0.f, 0.f};   // per-rr-slot l partials

    // gload staging: wave w stages rows 16w..16w+15 of each array.
    // Source quarter pre-swizzled: LDS slot (row,c) holds global quarter
    // c ^ sigma(row), sigma(row) = ((row&15)>>1)&3.
    const int srow = lane >> 2;
    const int sq = (lane & 3) ^ ((lane >> 3) & 3);
    const unsigned short* Kg = (const unsigned short*)K + base +
                               (size_t)(16 * w + srow) * D_ + sq * 8;
    const unsigned short* Vg = (const unsigned short*)Vt + base +
                               (size_t)(16 * w + srow) * S_ + sq * 8;

    // K-tile permuted row mapping: base row + per-i offsets
    const int kbase = 8 * (qm >> 2) + (qm & 3);
    // read quarter for K rows kappa: quad ^ sigma(kappa);
    // sigma(kappa) = ((qm>>1)&1) | ((i>>1)<<1)
    const int cqa = (quad ^ ((qm >> 1) & 1)) * 8;      // i = 0,1
    const int cqb = cqa ^ 16;                          // i = 2,3
    // V read quarter (rows 16jd+qm): quad ^ ((qm>>1)&3)
    const int cqv = (quad ^ ((qm >> 1) & 3)) * 8;

    // key offset per S^T tile i: key = kt*64 + 8*quad + o[i] + rr
    const int o_i[4] = {0, 32, 4, 36};

    // hoisted ALiBi constants
    const float scl = 0.18033688f;   // SCALE * log2(e)
    float cst[4], crr[4];
#pragma unroll
    for (int i = 0; i < 4; i++) cst[i] = -c2 * (float)(8 * quad + o_i[i]);
#pragma unroll
    for (int rr = 0; rr < 4; rr++) crr[rr] = -c2 * (float)rr;
    const int qi = bb + qm;

    auto body = [&](int kt, bool domask) {
        // async stage into LDS (block-level K/V de-dup: 1 copy serves 4 waves)
#pragma unroll
        for (int h = 0; h < 2; h++) {
            gload_lds16(Kg + (size_t)(kt * 64) * D_ + 32 * h, Ksm[h] + w * 512);
            gload_lds16(Vg + kt * 64 + 32 * h, Vsm[h] + w * 512);
        }
        __syncthreads();   // (compiler inserts vmcnt(0) drain before barrier)

        // K A-frags: permuted rows kbase + {0,32,4,36}; V B-frags as before
        bf16x8 ak[4][2], bv[4][2];
#pragma unroll
        for (int i = 0; i < 4; i++) {
            int row = kbase + o_i[i];
            int cqk = (i < 2) ? cqa : cqb;
            ak[i][0] = *(const bf16x8*)(Ksm[0] + row * 32 + cqk);
            ak[i][1] = *(const bf16x8*)(Ksm[1] + row * 32 + cqk);
        }
#pragma unroll
        for (int jd = 0; jd < 4; jd++) {
            bv[jd][0] = *(const bf16x8*)(Vsm[0] + (16 * jd + qm) * 32 + cqv);
            bv[jd][1] = *(const bf16x8*)(Vsm[1] + (16 * jd + qm) * 32 + cqv);
        }

        // S^T tiles: lane (qm,quad) reg rr holds S^T[key=8quad+o[i]+rr][q=qm]
        f32x4 st[4];
#pragma unroll
        for (int i = 0; i < 4; i++) {
            f32x4 zz = {0.f, 0.f, 0.f, 0.f};
            zz = __builtin_amdgcn_mfma_f32_16x16x32_bf16(ak[i][0], qf0, zz, 0, 0, 0);
            zz = __builtin_amdgcn_mfma_f32_16x16x32_bf16(ak[i][1], qf1, zz, 0, 0, 0);
            st[i] = zz;
        }

        // analytic-max softmax: exponent = qk*scl + kb + cst[i] + crr[rr]
        const float kb = -c2 * (float)(kt * 64);
        unsigned pk[4][2];
#pragma unroll
        for (int i = 0; i < 4; i++) {
            float bi = kb + cst[i];
            float p[4];
#pragma unroll
            for (int rr = 0; rr < 4; rr++) {
                float tt = st[i][rr] * scl + (bi + crr[rr]);
                float pp = __builtin_amdgcn_exp2f(tt);
                if (domask) {
                    int key = kt * 64 + 8 * quad + o_i[i] + rr;
                    pp = (key > qi) ? 0.f : pp;
                }
                lsv[rr] += pp;      // 4 independent accumulator chains
                p[rr] = pp;
            }
            // pack 4 fp32 -> 2 dwords of bf16 (RTNE, 1 op per pair)
            asm("v_cvt_pk_bf16_f32 %0, %1, %2"
                : "=v"(pk[i][0]) : "v"(p[0]), "v"(p[1]));
            asm("v_cvt_pk_bf16_f32 %0, %1, %2"
                : "=v"(pk[i][1]) : "v"(p[2]), "v"(p[3]));
        }

        // PV A-frags are LANE-LOCAL: ap0 = keys 8quad+{0..7} (tiles 0,2),
        // ap1 = keys 32+8quad+{0..7} (tiles 1,3). Pure register assembly.
        uint32x4 w0 = {pk[0][0], pk[0][1], pk[2][0], pk[2][1]};
        uint32x4 w1 = {pk[1][0], pk[1][1], pk[3][0], pk[3][1]};
        bf16x8 ap0 = __builtin_bit_cast(bf16x8, w0);
        bf16x8 ap1 = __builtin_bit_cast(bf16x8, w1);
#pragma unroll
        for (int jd = 0; jd < 4; jd++) {
            oacc[jd] = __builtin_amdgcn_mfma_f32_16x16x32_bf16(
                ap0, bv[jd][0], oacc[jd], 0, 0, 0);
            oacc[jd] = __builtin_amdgcn_mfma_f32_16x16x32_bf16(
                ap1, bv[jd][1], oacc[jd], 0, 0, 0);
        }

        __syncthreads();   // protect buffers before next iteration's gloads
    };

    for (int kt = 0; kt < qt; kt++) body(kt, false);  // mask-free main loop
    body(qt, true);                                   // peeled masked tile

    // epilogue: reduce l across quads (lane-local rows), divide, store
    float lf = (lsv[0] + lsv[1]) + (lsv[2] + lsv[3]);
    lf += __shfl_xor(lf, 16);
    lf += __shfl_xor(lf, 32);               // full l for q = bb+qm
#pragma unroll
    for (int rr = 0; rr < 4; rr++) {
        float lr = __shfl(lf, 4 * quad + rr);  // l for q = bb+4quad+rr
        float inv = 1.0f / lr;
        int qrow = bb + 4 * quad + rr;
#pragma unroll
        for (int jd = 0; jd < 4; jd++)
            O[base + (size_t)qrow * D_ + 16 * jd + qm] =
                f2bf(oacc[jd][rr] * inv);
    }
}

// ---------------------------------------------------------------------------
extern "C" void kernel_launch(void* const* d_in, const int* in_sizes, int n_in,
                              void* d_out, int out_size, void* d_ws, size_t ws_size,
                              hipStream_t stream) {
    (void)in_sizes; (void)n_in; (void)out_size; (void)ws_size;
    const float* x  = (const float*)d_in[0];
    const float* Wq = (const float*)d_in[1];
    const float* bq = (const float*)d_in[2];
    const float* Wk = (const float*)d_in[3];
    const float* bk = (const float*)d_in[4];
    const float* Wv = (const float*)d_in[5];
    const float* bv = (const float*)d_in[6];
    const float* Wo = (const float*)d_in[7];
    const float* bo = (const float*)d_in[8];
    float* out = (float*)d_out;

    const size_t n = (size_t)B_ * H_ * S_ * D_;  // 6291456
    // ws layout (46 MB):
    //  [0,n):   xb (dead after QKV gemm)
    //  [n,2n):  Qb -> Ob (attn reads only its own Q rows before writing them)
    //  [2n,3n): Kb
    //  [3n,4n): Vtb  (V written transposed by QKV gemm epilogue)
    //  [4n,+):  Wt, 4 x 768*768 bf16
    __bf16* xb  = (__bf16*)d_ws;
    __bf16* Qb  = xb + n;
    __bf16* Kb  = xb + 2 * n;
    __bf16* Vtb = xb + 3 * n;
    __bf16* Wt  = xb + 4 * n;
    __bf16* Ob  = Qb;

    prep<<<6720, 256, 0, stream>>>(x, xb, Wq, Wk, Wv, Wo, Wt);
    qkv_gemm<<<dim3(12, 128), 256, 0, stream>>>(
        xb, Wt, bq, bk, bv, Qb, Kb, Vtb);
    attn_k<<<1536, 256, 0, stream>>>(Qb, Kb, Vtb, Ob);
    gemm_out<<<dim3(12, 128), 256, 0, stream>>>(
        Ob, Wt + 3 * (size_t)E_ * E_, bo, out);
}

// Round 20
// 200.618 us; speedup vs baseline: 1.1389x; 1.1389x over previous
//
#include <hip/hip_runtime.h>
#include <hip/hip_bf16.h>
#include <cstdint>
#include <cstddef>

#define B_ 4
#define S_ 2048
#define E_ 768
#define H_ 12
#define D_ 64

typedef __bf16 bf16x8 __attribute__((ext_vector_type(8)));
typedef float f32x4 __attribute__((ext_vector_type(4)));
typedef unsigned uint32x4 __attribute__((ext_vector_type(4)));

__constant__ float c_slopes[12] = {
    0.6299605249f, 0.396850263f, 0.25f, 0.1574901312f,
    0.0992125657f, 0.0625f, 0.0393725328f, 0.0248031414f,
    0.015625f, 0.0098431332f, 0.0062007854f, 0.00390625f};

__device__ __forceinline__ unsigned short f2bf_u(float f) {
    unsigned u = __builtin_bit_cast(unsigned, f);
    u += 0x7fffu + ((u >> 16) & 1u);   // round-to-nearest-even
    return (unsigned short)(u >> 16);
}
__device__ __forceinline__ __bf16 f2bf(float f) {
    unsigned short s = f2bf_u(f);
    return __builtin_bit_cast(__bf16, s);
}

// async global->LDS, 16B per lane, dest = wave-uniform base + lane*16
__device__ __forceinline__ void gload_lds16(const void* g, void* l) {
    __builtin_amdgcn_global_load_lds(
        (const __attribute__((address_space(1))) unsigned int*)g,
        (__attribute__((address_space(3))) unsigned int*)l, 16, 0, 0);
}

// ---------------------------------------------------------------------------
// merged prep kernel. Blocks [0,6144): x fp32->bf16. Blocks [6144,6720):
// W fp32 [k][n] -> Wt bf16 [n][k].
// ---------------------------------------------------------------------------
__global__ __launch_bounds__(256) void prep(
    const float* __restrict__ x, __bf16* __restrict__ xb,
    const float* __restrict__ W0, const float* __restrict__ W1,
    const float* __restrict__ W2, const float* __restrict__ W3,
    __bf16* __restrict__ Wt) {
    __shared__ alignas(16) __bf16 ts[64 * 72];
    const int L = blockIdx.x;
    const int t = threadIdx.x;
    if (L < 6144) {
        int i = (L * 256 + t) * 4;
        float4 v = *(const float4*)(x + i);
        ushort4 o;
        o.x = f2bf_u(v.x); o.y = f2bf_u(v.y); o.z = f2bf_u(v.z); o.w = f2bf_u(v.w);
        *(ushort4*)((unsigned short*)xb + i) = o;
        return;
    }
    const int id = L - 6144;
    const int z = id / 144, rem = id % 144;
    const int k0 = (rem / 12) * 64, n0 = (rem % 12) * 64;
    const float* W = z == 0 ? W0 : z == 1 ? W1 : z == 2 ? W2 : W3;
    __bf16* out = Wt + (size_t)z * E_ * E_;
#pragma unroll
    for (int i = 0; i < 4; i++) {
        int idx = i * 256 + t;          // 1024 float4 chunks
        int row = idx >> 4, c4 = idx & 15;
        float4 v = *(const float4*)(W + (size_t)(k0 + row) * E_ + n0 + c4 * 4);
        ts[(c4 * 4 + 0) * 72 + row] = f2bf(v.x);
        ts[(c4 * 4 + 1) * 72 + row] = f2bf(v.y);
        ts[(c4 * 4 + 2) * 72 + row] = f2bf(v.z);
        ts[(c4 * 4 + 3) * 72 + row] = f2bf(v.w);
    }
    __syncthreads();
#pragma unroll
    for (int i = 0; i < 2; i++) {
        int idx = i * 256 + t;          // 512 chunks of 8 bf16
        int r = idx >> 3, c8 = idx & 7;
        *(uint4*)((unsigned short*)out + (size_t)(n0 + r) * E_ + k0 + c8 * 8) =
            *(const uint4*)((const unsigned short*)ts + r * 72 + c8 * 8);
    }
}

// ---------------------------------------------------------------------------
// FUSED QKV GEMM, R29: R27's reuse-optimal 128M x 64N x 3z body (R28's
// 64M retile raised bytes/FLOP 1.5x and regressed: FETCH 56MB, 61us),
// plus XCD-LOCAL BLOCK SWIZZLE: with the natural (12,64) grid the 12
// blocks sharing an A-panel had consecutive linear ids -> spread over all
// 8 XCDs -> each 196KB A-panel fetched ~8x. Remap (1D grid, 768 = 8*96):
//   r = L&7 (XCD, HW round-robin), y = r + 8*((L>>3)&7), x = L>>6.
// All 12 same-panel blocks + 8 panels land on ONE XCD: A 1.6MB + W 3.5MB
// ~ L2-resident per XCD. Pure bijection on the verified body.
// ---------------------------------------------------------------------------
__global__ __launch_bounds__(256, 3) void qkv_gemm(
    const __bf16* __restrict__ A, const __bf16* __restrict__ WtAll,
    const float* __restrict__ b0, const float* __restrict__ b1,
    const float* __restrict__ b2, __bf16* __restrict__ Qb,
    __bf16* __restrict__ Kb, __bf16* __restrict__ Vtb) {
    constexpr int Kd = E_;
    __shared__ alignas(16) __bf16 Asm[2][128 * 32];     // 16KB
    __shared__ alignas(16) __bf16 Bsm[2][3][64 * 32];   // 24KB

    const int t = threadIdx.x;
    const int w = t >> 6, lane = t & 63;
    const int qm = lane & 15, quad = lane >> 4;
    // XCD-local swizzle: same-A-panel blocks colocate on one XCD
    const int L = blockIdx.x;
    const int m0 = ((L & 7) + 8 * ((L >> 3) & 7)) * 128;
    const int n0 = (L >> 6) * 64;
    const int wm = w * 32;                 // wave owns 32 rows x 64 cols (x3 z)

    float bvv[3][4];
    const float* bs[3] = {b0, b1, b2};
#pragma unroll
    for (int z = 0; z < 3; z++)
#pragma unroll
        for (int j = 0; j < 4; j++) bvv[z][j] = bs[z][n0 + j * 16 + qm];

    const int crow = lane >> 2;                      // row within 16-row chunk
    const int scol = (lane & 3) ^ ((lane >> 3) & 3); // swizzled SOURCE quarter
    const int cq = (quad ^ ((qm >> 1) & 3)) * 8;     // swizzled read quarter

    f32x4 acc[3][2][4] = {};

    for (int k0 = 0; k0 < Kd; k0 += 64) {
#pragma unroll
        for (int p = 0; p < 2; p++) {
            const int kp = k0 + p * 32;
#pragma unroll
            for (int cc = 0; cc < 2; cc++) {
                int chunk = w * 2 + cc;
                gload_lds16((const unsigned short*)A +
                                (size_t)(m0 + chunk * 16 + crow) * Kd + kp + scol * 8,
                            Asm[p] + chunk * 512);
            }
#pragma unroll
            for (int e = 0; e < 3; e++) {
                int g = w * 3 + e;
                int z = g >> 2, cz = g & 3;
                gload_lds16((const unsigned short*)WtAll + (size_t)z * Kd * E_ +
                                (size_t)(n0 + cz * 16 + crow) * Kd + kp + scol * 8,
                            Bsm[p][z] + cz * 512);
            }
        }
        __syncthreads();

#pragma unroll
        for (int p = 0; p < 2; p++) {
            bf16x8 af[2];
#pragma unroll
            for (int i = 0; i < 2; i++)
                af[i] = *(const bf16x8*)(Asm[p] + (wm + i * 16 + qm) * 32 + cq);
#pragma unroll
            for (int z = 0; z < 3; z++) {
                bf16x8 bg[4];
#pragma unroll
                for (int j = 0; j < 4; j++)
                    bg[j] = *(const bf16x8*)(Bsm[p][z] + (j * 16 + qm) * 32 + cq);
#pragma unroll
                for (int i = 0; i < 2; i++)
#pragma unroll
                    for (int j = 0; j < 4; j++)
                        acc[z][i][j] = __builtin_amdgcn_mfma_f32_16x16x32_bf16(
                            af[i], bg[j], acc[z][i][j], 0, 0, 0);
            }
        }
        __syncthreads();
    }

    // epilogue: C/D layout col=lane&15, row=quad*4+reg
#pragma unroll
    for (int z = 0; z < 3; z++) {
        __bf16* out = z == 0 ? Qb : z == 1 ? Kb : Vtb;
#pragma unroll
        for (int i = 0; i < 2; i++) {
#pragma unroll
            for (int j = 0; j < 4; j++) {
                int col = n0 + j * 16 + qm;
                int rowb = m0 + wm + i * 16 + quad * 4;
                int h = col >> 6, d = col & (D_ - 1);
                if (z == 2) {
                    int b = rowb >> 11, s = rowb & (S_ - 1);
                    unsigned short pk4[4];
#pragma unroll
                    for (int r = 0; r < 4; r++)
                        pk4[r] = f2bf_u(acc[z][i][j][r] + bvv[z][j]);
                    uint2 pv;
                    pv.x = (unsigned)pk4[0] | ((unsigned)pk4[1] << 16);
                    pv.y = (unsigned)pk4[2] | ((unsigned)pk4[3] << 16);
                    *(uint2*)((unsigned short*)out +
                              ((size_t)(b * H_ + h) * D_ + d) * S_ + s) = pv;
                } else {
#pragma unroll
                    for (int r = 0; r < 4; r++) {
                        int row = rowb + r;
                        int b = row >> 11, s = row & (S_ - 1);
                        out[(((size_t)(b * H_ + h)) * S_ + s) * D_ + d] =
                            f2bf(acc[z][i][j][r] + bvv[z][j]);
                    }
                }
            }
        }
    }
}

// ---------------------------------------------------------------------------
// Output projection GEMM, R29: R27 body + same XCD-local swizzle.
// ---------------------------------------------------------------------------
__global__ __launch_bounds__(256, 3) void gemm_out(
    const __bf16* __restrict__ A, const __bf16* __restrict__ Wt,
    const float* __restrict__ bias, float* __restrict__ outF) {
    constexpr int Kd = E_, N = E_;
    __shared__ alignas(16) __bf16 Asm[2][128 * 32];   // 16KB
    __shared__ alignas(16) __bf16 Bsm[2][64 * 32];    // 8KB

    const int t = threadIdx.x;
    const int w = t >> 6, lane = t & 63;
    const int qm = lane & 15, quad = lane >> 4;
    const int L = blockIdx.x;
    const int m0 = ((L & 7) + 8 * ((L >> 3) & 7)) * 128;
    const int n0 = (L >> 6) * 64;
    const int wm = w * 32;

    float bvv[4];
#pragma unroll
    for (int j = 0; j < 4; j++) bvv[j] = bias[n0 + j * 16 + qm];

    const int crow = lane >> 2;
    const int scol = (lane & 3) ^ ((lane >> 3) & 3); // swizzled SOURCE quarter
    const int cq = (quad ^ ((qm >> 1) & 3)) * 8;     // swizzled read quarter

    f32x4 acc[2][4] = {};

    for (int k0 = 0; k0 < Kd; k0 += 64) {
#pragma unroll
        for (int p = 0; p < 2; p++) {
            const int kp = k0 + p * 32;
#pragma unroll
            for (int cc = 0; cc < 2; cc++) {
                int chunk = w * 2 + cc;
                gload_lds16((const unsigned short*)A +
                                (size_t)(m0 + chunk * 16 + crow) * Kd + kp + scol * 8,
                            Asm[p] + chunk * 512);
            }
            gload_lds16((const unsigned short*)Wt +
                            (size_t)(n0 + w * 16 + crow) * Kd + kp + scol * 8,
                        Bsm[p] + w * 512);
        }
        __syncthreads();

#pragma unroll
        for (int p = 0; p < 2; p++) {
            bf16x8 af[2], bg[4];
#pragma unroll
            for (int i = 0; i < 2; i++)
                af[i] = *(const bf16x8*)(Asm[p] + (wm + i * 16 + qm) * 32 + cq);
#pragma unroll
            for (int j = 0; j < 4; j++)
                bg[j] = *(const bf16x8*)(Bsm[p] + (j * 16 + qm) * 32 + cq);
#pragma unroll
            for (int i = 0; i < 2; i++)
#pragma unroll
                for (int j = 0; j < 4; j++)
                    acc[i][j] = __builtin_amdgcn_mfma_f32_16x16x32_bf16(
                        af[i], bg[j], acc[i][j], 0, 0, 0);
        }
        __syncthreads();
    }

#pragma unroll
    for (int i = 0; i < 2; i++) {
#pragma unroll
        for (int j = 0; j < 4; j++) {
            int col = n0 + j * 16 + qm;
            int rowb = m0 + wm + i * 16 + quad * 4;
#pragma unroll
            for (int r = 0; r < 4; r++)
                outF[(size_t)(rowb + r) * N + col] = acc[i][j][r] + bvv[j];
        }
    }
}

// ---------------------------------------------------------------------------
// Flash attention (R27 body, kept byte-identical - the control at 52.6us).
// Mirrored-slot exact balance; zero-LDS P via kappa row remap; unpaired;
// 6 blocks/CU; lsv f32x4. setprio blacklisted (R24).
// ---------------------------------------------------------------------------
__global__ __launch_bounds__(256, 6) void attn_k(
    const __bf16* __restrict__ Q, const __bf16* __restrict__ K,
    const __bf16* __restrict__ Vt, __bf16* __restrict__ O) {
    __shared__ alignas(16) __bf16 Ksm[2][64 * 32];   // [dhalf][key][d%32] swz
    __shared__ alignas(16) __bf16 Vsm[2][64 * 32];   // [khalf][d][key%32] swz

    const int t = threadIdx.x;
    const int w = t >> 6, lane = t & 63;
    const int qm = lane & 15, quad = lane >> 4;
    // balanced XCD-local block swizzle, mirrored-slot exact balance
    const int L = blockIdx.x;
    const int r = L & 7;            // XCD (round-robin)
    const int m = (L >> 3) & 31;    // CU within XCD
    const int s = L >> 8;           // co-resident slot 0..5
    const int bh = r * 6 + s;       // 6 fixed heads per XCD
    const int so = (s % 3) * 5 + ((s % 3) >> 1);   // 0,5,11
    const int qt = (s < 3) ? ((m + so) & 31) : ((31 - m - so) & 31);
    const float c2 = c_slopes[bh % H_] * 1.44269504f;     // slope * log2(e)
    const size_t base = (size_t)bh * S_ * D_;

    // Q B-fragments (lane qm = q-col, contiguous over d)
    const int bb = qt * 64 + w * 16;
    const __bf16* qp = Q + base + (size_t)(bb + qm) * D_ + quad * 8;
    bf16x8 qf0 = *(const bf16x8*)qp;
    bf16x8 qf1 = *(const bf16x8*)(qp + 32);

    f32x4 oacc[4] = {};
    f32x4 lsv = {0.f, 0.f, 0.f, 0.f};   // per-rr-slot l partials

    // gload staging: wave w stages rows 16w..16w+15 of each array.
    // Source quarter pre-swizzled: LDS slot (row,c) holds global quarter
    // c ^ sigma(row), sigma(row) = ((row&15)>>1)&3.
    const int srow = lane >> 2;
    const int sq = (lane & 3) ^ ((lane >> 3) & 3);
    const unsigned short* Kg = (const unsigned short*)K + base +
                               (size_t)(16 * w + srow) * D_ + sq * 8;
    const unsigned short* Vg = (const unsigned short*)Vt + base +
                               (size_t)(16 * w + srow) * S_ + sq * 8;

    // K-tile permuted row mapping: base row + per-i offsets
    const int kbase = 8 * (qm >> 2) + (qm & 3);
    // read quarter for K rows kappa: quad ^ sigma(kappa);
    // sigma(kappa) = ((qm>>1)&1) | ((i>>1)<<1)
    const int cqa = (quad ^ ((qm >> 1) & 1)) * 8;      // i = 0,1
    const int cqb = cqa ^ 16;                          // i = 2,3
    // V read quarter (rows 16jd+qm): quad ^ ((qm>>1)&3)
    const int cqv = (quad ^ ((qm >> 1) & 3)) * 8;

    // key offset per S^T tile i: key = kt*64 + 8*quad + o[i] + rr
    const int o_i[4] = {0, 32, 4, 36};

    // hoisted ALiBi constants
    const float scl = 0.18033688f;   // SCALE * log2(e)
    float cst[4], crr[4];
#pragma unroll
    for (int i = 0; i < 4; i++) cst[i] = -c2 * (float)(8 * quad + o_i[i]);
#pragma unroll
    for (int rr = 0; rr < 4; rr++) crr[rr] = -c2 * (float)rr;
    const int qi = bb + qm;

    auto body = [&](int kt, bool domask) {
        // async stage into LDS (block-level K/V de-dup: 1 copy serves 4 waves)
#pragma unroll
        for (int h = 0; h < 2; h++) {
            gload_lds16(Kg + (size_t)(kt * 64) * D_ + 32 * h, Ksm[h] + w * 512);
            gload_lds16(Vg + kt * 64 + 32 * h, Vsm[h] + w * 512);
        }
        __syncthreads();   // (compiler inserts vmcnt(0) drain before barrier)

        // K A-frags: permuted rows kbase + {0,32,4,36}; V B-frags as before
        bf16x8 ak[4][2], bv[4][2];
#pragma unroll
        for (int i = 0; i < 4; i++) {
            int row = kbase + o_i[i];
            int cqk = (i < 2) ? cqa : cqb;
            ak[i][0] = *(const bf16x8*)(Ksm[0] + row * 32 + cqk);
            ak[i][1] = *(const bf16x8*)(Ksm[1] + row * 32 + cqk);
        }
#pragma unroll
        for (int jd = 0; jd < 4; jd++) {
            bv[jd][0] = *(const bf16x8*)(Vsm[0] + (16 * jd + qm) * 32 + cqv);
            bv[jd][1] = *(const bf16x8*)(Vsm[1] + (16 * jd + qm) * 32 + cqv);
        }

        // S^T tiles: lane (qm,quad) reg rr holds S^T[key=8quad+o[i]+rr][q=qm]
        f32x4 st[4];
#pragma unroll
        for (int i = 0; i < 4; i++) {
            f32x4 zz = {0.f, 0.f, 0.f, 0.f};
            zz = __builtin_amdgcn_mfma_f32_16x16x32_bf16(ak[i][0], qf0, zz, 0, 0, 0);
            zz = __builtin_amdgcn_mfma_f32_16x16x32_bf16(ak[i][1], qf1, zz, 0, 0, 0);
            st[i] = zz;
        }

        // analytic-max softmax: exponent = qk*scl + kb + cst[i] + crr[rr]
        const float kb = -c2 * (float)(kt * 64);
        unsigned pk[4][2];
#pragma unroll
        for (int i = 0; i < 4; i++) {
            float bi = kb + cst[i];
            float p[4];
#pragma unroll
            for (int rr = 0; rr < 4; rr++) {
                float tt = st[i][rr] * scl + (bi + crr[rr]);
                float pp = __builtin_amdgcn_exp2f(tt);
                if (domask) {
                    int key = kt * 64 + 8 * quad + o_i[i] + rr;
                    pp = (key > qi) ? 0.f : pp;
                }
                lsv[rr] += pp;      // 4 independent accumulator chains
                p[rr] = pp;
            }
            // pack 4 fp32 -> 2 dwords of bf16 (RTNE, 1 op per pair)
            asm("v_cvt_pk_bf16_f32 %0, %1, %2"
                : "=v"(pk[i][0]) : "v"(p[0]), "v"(p[1]));
            asm("v_cvt_pk_bf16_f32 %0, %1, %2"
                : "=v"(pk[i][1]) : "v"(p[2]), "v"(p[3]));
        }

        // PV A-frags are LANE-LOCAL: ap0 = keys 8quad+{0..7} (tiles 0,2),
        // ap1 = keys 32+8quad+{0..7} (tiles 1,3). Pure register assembly.
        uint32x4 w0 = {pk[0][0], pk[0][1], pk[2][0], pk[2][1]};
        uint32x4 w1 = {pk[1][0], pk[1][1], pk[3][0], pk[3][1]};
        bf16x8 ap0 = __builtin_bit_cast(bf16x8, w0);
        bf16x8 ap1 = __builtin_bit_cast(bf16x8, w1);
#pragma unroll
        for (int jd = 0; jd < 4; jd++) {
            oacc[jd] = __builtin_amdgcn_mfma_f32_16x16x32_bf16(
                ap0, bv[jd][0], oacc[jd], 0, 0, 0);
            oacc[jd] = __builtin_amdgcn_mfma_f32_16x16x32_bf16(
                ap1, bv[jd][1], oacc[jd], 0, 0, 0);
        }

        __syncthreads();   // protect buffers before next iteration's gloads
    };

    for (int kt = 0; kt < qt; kt++) body(kt, false);  // mask-free main loop
    body(qt, true);                                   // peeled masked tile

    // epilogue: reduce l across quads (lane-local rows), divide, store
    float lf = (lsv[0] + lsv[1]) + (lsv[2] + lsv[3]);
    lf += __shfl_xor(lf, 16);
    lf += __shfl_xor(lf, 32);               // full l for q = bb+qm
#pragma unroll
    for (int rr = 0; rr < 4; rr++) {
        float lr = __shfl(lf, 4 * quad + rr);  // l for q = bb+4quad+rr
        float inv = 1.0f / lr;
        int qrow = bb + 4 * quad + rr;
#pragma unroll
        for (int jd = 0; jd < 4; jd++)
            O[base + (size_t)qrow * D_ + 16 * jd + qm] =
                f2bf(oacc[jd][rr] * inv);
    }
}

// ---------------------------------------------------------------------------
extern "C" void kernel_launch(void* const* d_in, const int* in_sizes, int n_in,
                              void* d_out, int out_size, void* d_ws, size_t ws_size,
                              hipStream_t stream) {
    (void)in_sizes; (void)n_in; (void)out_size; (void)ws_size;
    const float* x  = (const float*)d_in[0];
    const float* Wq = (const float*)d_in[1];
    const float* bq = (const float*)d_in[2];
    const float* Wk = (const float*)d_in[3];
    const float* bk = (const float*)d_in[4];
    const float* Wv = (const float*)d_in[5];
    const float* bv = (const float*)d_in[6];
    const float* Wo = (const float*)d_in[7];
    const float* bo = (const float*)d_in[8];
    float* out = (float*)d_out;

    const size_t n = (size_t)B_ * H_ * S_ * D_;  // 6291456
    // ws layout (46 MB):
    //  [0,n):   xb (dead after QKV gemm)
    //  [n,2n):  Qb -> Ob (attn reads only its own Q rows before writing them)
    //  [2n,3n): Kb
    //  [3n,4n): Vtb  (V written transposed by QKV gemm epilogue)
    //  [4n,+):  Wt, 4 x 768*768 bf16
    __bf16* xb  = (__bf16*)d_ws;
    __bf16* Qb  = xb + n;
    __bf16* Kb  = xb + 2 * n;
    __bf16* Vtb = xb + 3 * n;
    __bf16* Wt  = xb + 4 * n;
    __bf16* Ob  = Qb;

    prep<<<6720, 256, 0, stream>>>(x, xb, Wq, Wk, Wv, Wo, Wt);
    qkv_gemm<<<768, 256, 0, stream>>>(
        xb, Wt, bq, bk, bv, Qb, Kb, Vtb);
    attn_k<<<1536, 256, 0, stream>>>(Qb, Kb, Vtb, Ob);
    gemm_out<<<768, 256, 0, stream>>>(
        Ob, Wt + 3 * (size_t)E_ * E_, bo, out);
}